// Round 2
// baseline (178.243 us; speedup 1.0000x reference)
//
#include <hip/hip_runtime.h>
#include <hip/hip_bf16.h>

// out[tgt[i], :] += x[src[i], :] * e[i]   (fp32, D=32)
// One 32-lane group per edge; lane index = feature index.
// NOTE: harness delivers integer inputs as int32 (int64 in reference is
// converted) -> cast a to const int*.

#define D_FEAT 32

__global__ void zero_out_kernel(float* __restrict__ out, int n) {
    int i = blockIdx.x * blockDim.x + threadIdx.x;
    if (i < n) out[i] = 0.0f;
}

__global__ void scatter_add_kernel(const float* __restrict__ x,
                                   const int* __restrict__ src,
                                   const int* __restrict__ tgt,
                                   const float* __restrict__ e,
                                   float* __restrict__ out,
                                   int n_edges) {
    // grid-stride over (edge, feature) pairs; 32 threads per edge
    long long gid    = (long long)blockIdx.x * blockDim.x + threadIdx.x;
    long long stride = (long long)gridDim.x * blockDim.x;
    long long total  = (long long)n_edges * D_FEAT;

    for (long long idx = gid; idx < total; idx += stride) {
        int edge = (int)(idx >> 5);   // idx / 32
        int f    = (int)(idx & 31);

        int s    = src[edge];         // broadcast load across the 32-lane group
        int t    = tgt[edge];
        float ev = e[edge];

        float m = x[(long long)s * D_FEAT + f] * ev;
        atomicAdd(&out[(long long)t * D_FEAT + f], m);
    }
}

extern "C" void kernel_launch(void* const* d_in, const int* in_sizes, int n_in,
                              void* d_out, int out_size, void* d_ws, size_t ws_size,
                              hipStream_t stream) {
    const float* x = (const float*)d_in[0];
    const int*   a = (const int*)d_in[1];   // [2, n_edges], delivered as int32
    const float* e = (const float*)d_in[2];

    int n_edges = in_sizes[2];               // e has n_edges elements
    const int* src = a;                      // a[0, :]
    const int* tgt = a + n_edges;            // a[1, :]

    float* out = (float*)d_out;

    // zero the output (segment_sum semantics; harness poisons d_out)
    {
        int threads = 256;
        int blocks  = (out_size + threads - 1) / threads;
        zero_out_kernel<<<blocks, threads, 0, stream>>>(out, out_size);
    }

    // scatter-add: 32 threads per edge
    {
        long long total = (long long)n_edges * D_FEAT;
        int threads = 256;
        long long want = (total + threads - 1) / threads;
        int blocks = (want > 2097152LL) ? 2097152 : (int)want;  // grid-stride covers rest
        scatter_add_kernel<<<blocks, threads, 0, stream>>>(x, src, tgt, e, out, n_edges);
    }
}